// Round 1
// baseline (1521.872 us; speedup 1.0000x reference)
//
#include <hip/hip_runtime.h>
#include <math.h>

#define BB 128
#define QQ 200
#define CC 92
#define CMPAD (QQ * QQ + 64) // pad so c3 = crow[192+t] stays in-bounds for t<64

// ---------------------------------------------------------------------------
// Kernel 1: lse[b,i] = logsumexp(pred_cat[b,i,:]) over C=92 classes
// ---------------------------------------------------------------------------
__global__ void lse_kernel(const float* __restrict__ pc, float* __restrict__ lse) {
    int idx = blockIdx.x * blockDim.x + threadIdx.x;  // over B*Q
    if (idx >= BB * QQ) return;
    const float* row = pc + (size_t)idx * CC;
    float m = -INFINITY;
    for (int c = 0; c < CC; ++c) m = fmaxf(m, row[c]);
    float s = 0.f;
    for (int c = 0; c < CC; ++c) s += expf(row[c] - m);
    lse[idx] = m + logf(s);
}

// ---------------------------------------------------------------------------
// Kernel 2: cost[b,i,j] = CE + SmoothL1*mask
// ---------------------------------------------------------------------------
__global__ void cost_kernel(const float* __restrict__ pc,
                            const float* __restrict__ pb,
                            const int*   __restrict__ tc,
                            const float* __restrict__ tb,
                            const float* __restrict__ lse,
                            float* __restrict__ cost) {
    long idx = blockIdx.x * (long)blockDim.x + threadIdx.x;
    if (idx >= (long)BB * QQ * QQ) return;
    int j = (int)(idx % QQ);
    int i = (int)((idx / QQ) % QQ);
    int b = (int)(idx / ((long)QQ * QQ));
    int cls = tc[b * QQ + j];
    float ce = lse[b * QQ + i] - pc[((size_t)(b * QQ + i)) * CC + cls];
    const float* pbb = pb + ((size_t)(b * QQ + i)) * 4;
    const float* tbb = tb + ((size_t)(b * QQ + j)) * 4;
    float sl1 = 0.f;
#pragma unroll
    for (int k = 0; k < 4; ++k) {
        float d = pbb[k] - tbb[k];
        float ad = fabsf(d);
        sl1 += (ad < 1.f) ? 0.5f * d * d : (ad - 0.5f);
    }
    float mask = (cls != 0) ? 1.f : 0.f;
    cost[idx] = ce + sl1 * mask;
}

// ---------------------------------------------------------------------------
__device__ __forceinline__ int rdlane_i(int x, int l) { return __builtin_amdgcn_readlane(x, l); }
__device__ __forceinline__ float rdlane_f(float x, int l) {
    return __uint_as_float((unsigned)__builtin_amdgcn_readlane((int)__float_as_uint(x), l));
}

// wave64 float min-reduce via DPP (row_shr 1/2/4/8, row_bcast 15/31), result
// broadcast from lane 63 as an SGPR. Float domain (v_min_f32): jnp.argmin
// compares floats, so equality-ballot against this min reproduces its
// semantics exactly (incl. -0==+0). No NaNs in this data.
__device__ __forceinline__ float wave_fmin_bcast(float x) {
    float y;
#define DPPSTEP(ctrl) \
    y = __uint_as_float((unsigned)__builtin_amdgcn_update_dpp( \
            (int)__float_as_uint(x), (int)__float_as_uint(x), ctrl, 0xf, 0xf, false)); \
    x = fminf(x, y);
    DPPSTEP(0x111) DPPSTEP(0x112) DPPSTEP(0x114) DPPSTEP(0x118)
    DPPSTEP(0x142) DPPSTEP(0x143)
#undef DPPSTEP
    return rdlane_f(x, 63);
}

// ctz that is well-defined for 0 (returns 63; only consumed when mask known
// nonzero via the s_cselect chain) -> single s_ff1_i64, no branch.
__device__ __forceinline__ int ctz64(unsigned long long m) {
    return (int)__builtin_ctzll(m | 0x8000000000000000ull);
}

// ---------------------------------------------------------------------------
// Kernel 3: Hungarian (e-maxx JV, reference-identical values) — one 64-lane
// wave per batch. R10 = R9 with the loop-carried critical path compressed:
//   - pslot packed as 4xu8 in ONE VGPR pp  -> pi = bfe(readlane(pp,lane))
//     issues right after j1 (no cndmask chain before the readlane); the LDS
//     prefetch of the next row starts ~15 cyc earlier.
//   - branchless j1 (s_ff1 + s_cselect chain, no taken branches)
//   - used-masking via kv = minv + uadd (uadd in {0,1e9}); exact for unused
//     slots (x+0.0f==x); used/invalid slots sit >= 1e9-eps and can never win
//     (gmin <= ~1e2 always). way updates stay gated => reference-identical.
//   - mark-used moved to loop bottom (j1>0 there) — same timing as ref's
//     mark-at-top, kills the `if (j0>0)` branch.
//   - phase i+1 row prefetched before the augment walk.
// Lane t owns columns j = 1+t+64k (k=0..3; k=3 valid only for t<8).
// ---------------------------------------------------------------------------
__global__ __launch_bounds__(64) void hungarian_kernel(const float* __restrict__ cost,
                                                       float* __restrict__ out) {
    const int b = blockIdx.x;
    const int t = threadIdx.x;
    const float* cb = cost + (size_t)b * QQ * QQ;

    __shared__ __align__(16) float cm[CMPAD];

    // stage cost matrix into LDS (float4; single wave => in-order DS ops)
    {
        const float4* src = (const float4*)cb;
        float4* dst = (float4*)cm;
        for (int idx = t; idx < QQ * QQ / 4; idx += 64) dst[idx] = src[idx];
        cm[QQ * QQ + t] = 1e9f;   // pad: finite & huge, can never win an argmin
    }

    const float INF = 1e9f;
    const int nval = (t < 8) ? 4 : 3;          // slot k valid iff 1+t+64k <= 200
    const float a3init = (t < 8) ? 0.f : INF;  // invalid slot permanently "used"

    float v0 = 0.f, v1 = 0.f, v2 = 0.f, v3 = 0.f;      // column duals
    float us0 = 0.f, us1 = 0.f, us2 = 0.f, us3 = 0.f;  // u of row matched to col
    int pp = 0;                                        // packed u8 p per slot (0=free)

    // prefetch phase-1 row (row 0)
    float c0 = cm[t], c1 = cm[64 + t], c2 = cm[128 + t], c3 = cm[192 + t];

    for (int i = 1; i <= QQ; ++i) {
        float m0 = INF, m1 = INF, m2 = INF, m3 = INF;  // minv
        int w0 = 0, w1 = 0, w2 = 0, w3 = 0;            // way
        float a0 = 0.f, a1 = 0.f, a2 = 0.f, a3 = a3init; // uadd: 0=unused, INF=used
        float usent = 0.f;                             // u[i] accumulated (sentinel)
        float u0 = 0.f;                                // u[i0] for current iteration
        int j0 = 0;

        for (;;) {
            // ---- reduced costs of current row (ref fp order: (c-u0)-v)
            float r0 = (c0 - u0) - v0;
            float r1 = (c1 - u0) - v1;
            float r2 = (c2 - u0) - v2;
            float r3 = (c3 - u0) - v3;
            bool f0 = (a0 == 0.f), f1 = (a1 == 0.f), f2 = (a2 == 0.f), f3 = (a3 == 0.f);
            // way freezes for used slots; minv update ungated (used-slot drift is
            // hidden behind +1e9 and never read by ref-visible state)
            if (f0 & (r0 < m0)) w0 = j0;
            if (f1 & (r1 < m1)) w1 = j0;
            if (f2 & (r2 < m2)) w2 = j0;
            if (f3 & (r3 < m3)) w3 = j0;
            m0 = fminf(m0, r0); m1 = fminf(m1, r1);
            m2 = fminf(m2, r2); m3 = fminf(m3, r3);
            float kv0 = m0 + a0, kv1 = m1 + a1, kv2 = m2 + a2, kv3 = m3 + a3;

            float gmin = wave_fmin_bcast(fminf(fminf(kv0, kv1), fminf(kv2, kv3)));
            float delta = gmin;

            // ---- smallest j with kv==gmin: k-major, lowest lane (branchless)
            unsigned long long e0 = __ballot(kv0 == gmin);
            unsigned long long e1 = __ballot(kv1 == gmin);
            unsigned long long e2 = __ballot(kv2 == gmin);
            unsigned long long e3 = __ballot(kv3 == gmin);
            int j1 = 193 + ctz64(e3);
            j1 = e2 ? 129 + ctz64(e2) : j1;
            j1 = e1 ? 65 + ctz64(e1) : j1;
            j1 = e0 ? 1 + ctz64(e0) : j1;

            // ---- matched row from j1's owner lane: ONE readlane + scalar bfe
            int lm = (j1 - 1) & 63, km = (j1 - 1) >> 6;
            int pi = (rdlane_i(pp, lm) >> (km * 8)) & 255;

            // ---- issue next row's reads NOW (cm immutable: no hazard);
            //      ~120cyc latency overlaps u0n/updates/mark below
            int nr = (pi > 0 ? pi : 1) - 1;
            const float* nrow = cm + nr * QQ;
            float n0 = nrow[t], n1 = nrow[64 + t], n2 = nrow[128 + t], n3 = nrow[192 + t];

            // ---- u[p[j1]] (pre-update value == ref's read next iteration);
            //      off critical path (first needed when n0..n3 arrive)
            float uA = (km & 1) ? us1 : us0;
            float uB = (km & 1) ? us3 : us2;
            float u0n = rdlane_f((km & 2) ? uB : uA, lm);

            // ---- dual updates (identical fp sequence to reference for all
            //      reference-visible slots)
            float s0 = f0 ? 0.f : delta;
            float s1 = f1 ? 0.f : delta;
            float s2 = f2 ? 0.f : delta;
            float s3 = f3 ? 0.f : delta;
            v0 -= s0; us0 += s0; m0 -= delta;
            v1 -= s1; us1 += s1; m1 -= delta;
            v2 -= s2; us2 += s2; m2 -= delta;
            v3 -= s3; us3 += s3; m3 -= delta;
            usent += delta;                          // == u[i] += delta (sentinel)

            // ---- mark j1 used (effective next iteration == ref's mark-at-top)
            bool me = (t == lm);
            if (me & (km == 0)) a0 = INF;
            if (me & (km == 1)) a1 = INF;
            if (me & (km == 2)) a2 = INF;
            if (me & (km == 3)) a3 = INF;

            j0 = j1;
            if (pi == 0) break;
            u0 = u0n;
            c0 = n0; c1 = n1; c2 = n2; c3 = n3;
        }

        // ---- prefetch next phase's row; LDS latency hides under the augment
        if (i < QQ) {
            const float* prow = cm + i * QQ;       // row (i+1)-1, 0-based
            c0 = prow[t]; c1 = prow[64 + t]; c2 = prow[128 + t]; c3 = prow[192 + t];
        }

        // ---- augment: flip matching along alternating path (uniform walk;
        //      way/pp/us served from registers via readlane; entries frozen)
        int jj = j0;
        while (jj != 0) {
            int jm = jj - 1, kw = jm >> 6, lw = jm & 63;
            int wA = (kw & 1) ? w1 : w0;
            int wB = (kw & 1) ? w3 : w2;
            int jn = rdlane_i((kw & 2) ? wB : wA, lw);
            int pnew; float unew;
            if (jn == 0) {
                pnew = i;                            // p[0] = i (sentinel)
                unew = usent;                        // u[i] accumulated this phase
            } else {
                int jm2 = jn - 1, kn = jm2 >> 6, ln2 = jm2 & 63;
                pnew = (rdlane_i(pp, ln2) >> (kn * 8)) & 255;
                float yA = (kn & 1) ? us1 : us0;
                float yB = (kn & 1) ? us3 : us2;
                unew = rdlane_f((kn & 2) ? yB : yA, ln2);
            }
            if (lw == t) {
                int sh = kw * 8;
                pp = (pp & ~(255 << sh)) | (pnew << sh);
                if (kw == 0) us0 = unew;
                else if (kw == 1) us1 = unew;
                else if (kw == 2) us2 = unew;
                else us3 = unew;
            }
            jj = jn;
        }
    }

    // pp byte k = row matched to owned column 1+t+64k; emit per-row matched cost
#pragma unroll
    for (int k = 0; k < 4; ++k) {
        if (k < nval) {
            int jc = t + 64 * k;                     // 0-based column
            int row = ((pp >> (8 * k)) & 255) - 1;
            out[b * QQ + row] = cm[row * QQ + jc];
        }
    }
}

// ---------------------------------------------------------------------------
extern "C" void kernel_launch(void* const* d_in, const int* in_sizes, int n_in,
                              void* d_out, int out_size, void* d_ws, size_t ws_size,
                              hipStream_t stream) {
    const float* pred_cat  = (const float*)d_in[0];
    const float* pred_bbox = (const float*)d_in[1];
    const int*   tar_cat   = (const int*)d_in[2];
    const float* tar_bbox  = (const float*)d_in[3];
    float* out = (float*)d_out;

    float* cost = (float*)d_ws;                     // B*Q*Q floats = 20.48 MB
    float* lse  = cost + (size_t)BB * QQ * QQ;      // B*Q floats

    lse_kernel<<<(BB * QQ + 255) / 256, 256, 0, stream>>>(pred_cat, lse);
    cost_kernel<<<((long)BB * QQ * QQ + 255) / 256, 256, 0, stream>>>(
        pred_cat, pred_bbox, tar_cat, tar_bbox, lse, cost);
    hungarian_kernel<<<BB, 64, 0, stream>>>(cost, out);
}

// Round 3
// 1376.992 us; speedup vs baseline: 1.1052x; 1.1052x over previous
//
#include <hip/hip_runtime.h>
#include <math.h>

#define BB 128
#define QQ 200
#define CC 92
#define CMPAD (QQ * QQ + 64) // pad so c3 = crow[192+t] stays in-bounds for t<64

// ---------------------------------------------------------------------------
// Kernel 1: lse[b,i] = logsumexp(pred_cat[b,i,:]) over C=92 classes
// ---------------------------------------------------------------------------
__global__ void lse_kernel(const float* __restrict__ pc, float* __restrict__ lse) {
    int idx = blockIdx.x * blockDim.x + threadIdx.x;  // over B*Q
    if (idx >= BB * QQ) return;
    const float* row = pc + (size_t)idx * CC;
    float m = -INFINITY;
    for (int c = 0; c < CC; ++c) m = fmaxf(m, row[c]);
    float s = 0.f;
    for (int c = 0; c < CC; ++c) s += expf(row[c] - m);
    lse[idx] = m + logf(s);
}

// ---------------------------------------------------------------------------
// Kernel 2: cost[b,i,j] = CE + SmoothL1*mask
// ---------------------------------------------------------------------------
__global__ void cost_kernel(const float* __restrict__ pc,
                            const float* __restrict__ pb,
                            const int*   __restrict__ tc,
                            const float* __restrict__ tb,
                            const float* __restrict__ lse,
                            float* __restrict__ cost) {
    long idx = blockIdx.x * (long)blockDim.x + threadIdx.x;
    if (idx >= (long)BB * QQ * QQ) return;
    int j = (int)(idx % QQ);
    int i = (int)((idx / QQ) % QQ);
    int b = (int)(idx / ((long)QQ * QQ));
    int cls = tc[b * QQ + j];
    float ce = lse[b * QQ + i] - pc[((size_t)(b * QQ + i)) * CC + cls];
    const float* pbb = pb + ((size_t)(b * QQ + i)) * 4;
    const float* tbb = tb + ((size_t)(b * QQ + j)) * 4;
    float sl1 = 0.f;
#pragma unroll
    for (int k = 0; k < 4; ++k) {
        float d = pbb[k] - tbb[k];
        float ad = fabsf(d);
        sl1 += (ad < 1.f) ? 0.5f * d * d : (ad - 0.5f);
    }
    float mask = (cls != 0) ? 1.f : 0.f;
    cost[idx] = ce + sl1 * mask;
}

// ---------------------------------------------------------------------------
__device__ __forceinline__ int rdlane_i(int x, int l) { return __builtin_amdgcn_readlane(x, l); }
__device__ __forceinline__ float rdlane_f(float x, int l) {
    return __uint_as_float((unsigned)__builtin_amdgcn_readlane((int)__float_as_uint(x), l));
}

// wave64 float min-reduce via DPP (row_shr 1/2/4/8, row_bcast 15/31), result
// broadcast from lane 63 as an SGPR. Float domain (v_min_f32): jnp.argmin
// compares floats, so equality-ballot against this min reproduces its
// semantics exactly (incl. -0==+0). No NaNs in this data.
__device__ __forceinline__ float wave_fmin_bcast(float x) {
    float y;
#define DPPSTEP(ctrl) \
    y = __uint_as_float((unsigned)__builtin_amdgcn_update_dpp( \
            (int)__float_as_uint(x), (int)__float_as_uint(x), ctrl, 0xf, 0xf, false)); \
    x = fminf(x, y);
    DPPSTEP(0x111) DPPSTEP(0x112) DPPSTEP(0x114) DPPSTEP(0x118)
    DPPSTEP(0x142) DPPSTEP(0x143)
#undef DPPSTEP
    return rdlane_f(x, 63);
}

// ---------------------------------------------------------------------------
// Kernel 3: Hungarian (e-maxx JV, reference trajectory bit-for-bit) — one
// 64-lane wave per batch. R12 = R9 (the measured-best 1372us kernel) plus
// EXACTLY ONE change, isolated for bisection after R11's failure:
//   a redundant packed copy of pslot (4xu8 in unsigned `pp`, maintained
//   alongside pslot in the augment walk) feeds the inner-loop matched-row
//   lookup:  pi = (readlane(pp, ln) >> 8*kk) & 255.
//   This removes the 3-deep cndmask select chain between j1 and the
//   readlane gating the next row's ds_read (~120cyc carried latency), so
//   the scheduler can issue the LDS read ~12-15 cyc earlier per pop.
// Everything else (pslot arrays, phase-local crow loads, us-select
// position, augment reads, output stage) is byte-for-byte R9.
// Lane t owns columns j = 1+t+64k (k=0..3; k=3 valid only for t<8).
// ---------------------------------------------------------------------------
__global__ __launch_bounds__(64) void hungarian_kernel(const float* __restrict__ cost,
                                                       float* __restrict__ out) {
    const int b = blockIdx.x;
    const int t = threadIdx.x;
    const float* cb = cost + (size_t)b * QQ * QQ;

    __shared__ __align__(16) float cm[CMPAD];

    // stage cost matrix into LDS (float4; single wave => in-order DS ops)
    {
        const float4* src = (const float4*)cb;
        float4* dst = (float4*)cm;
        for (int idx = t; idx < QQ * QQ / 4; idx += 64) dst[idx] = src[idx];
    }

    const float INF = 1e9f;
    const int nval = (t < 8) ? 4 : 3;   // slot k valid iff 1+t+64k <= 200

    float v[4]     = {0.f, 0.f, 0.f, 0.f};
    int   pslot[4] = {0, 0, 0, 0};      // p for owned columns (0 = free)
    unsigned pp    = 0u;                // packed u8 shadow of pslot
    float uslot[4] = {0.f, 0.f, 0.f, 0.f};  // u of row matched to owned column
    float minv[4];
    int   waysl[4];
    int   usedm;
    float usent;

    for (int i = 1; i <= QQ; ++i) {
        minv[0] = minv[1] = minv[2] = minv[3] = INF;
        waysl[0] = waysl[1] = waysl[2] = waysl[3] = 0;
        usedm = 0;
        usent = 0.f;                    // u[i] == 0 at phase start
        int j0 = 0;
        float u0 = 0.f;                 // u[i0] for current iteration
        const float* crow = cm + (i - 1) * QQ;
        float c0 = crow[t];
        float c1 = crow[64 + t];
        float c2 = crow[128 + t];
        float c3 = crow[192 + t];       // pad keeps this in-bounds

        for (;;) {
            // ---- mark j0 used (owner lane)
            if (j0 > 0) {
                int s = (j0 - 1) >> 6;
                if (((j0 - 1) & 63) == t) usedm |= 1 << s;
            }

            // ---- scan owned columns (gated on !used: way entries freeze)
            float kv0, kv1, kv2, kv3;
            {
                float cur;
                cur = c0 - u0 - v[0];
                if (!(usedm & 1) && cur < minv[0]) { minv[0] = cur; waysl[0] = j0; }
                kv0 = (usedm & 1) ? INF : minv[0];
                cur = c1 - u0 - v[1];
                if (!(usedm & 2) && cur < minv[1]) { minv[1] = cur; waysl[1] = j0; }
                kv1 = (usedm & 2) ? INF : minv[1];
                cur = c2 - u0 - v[2];
                if (!(usedm & 4) && cur < minv[2]) { minv[2] = cur; waysl[2] = j0; }
                kv2 = (usedm & 4) ? INF : minv[2];
                cur = c3 - u0 - v[3];
                if (!(usedm & 8) && t < 8 && cur < minv[3]) { minv[3] = cur; waysl[3] = j0; }
                kv3 = ((usedm & 8) || t >= 8) ? INF : minv[3];
            }

            float gmin = wave_fmin_bcast(fminf(fminf(kv0, kv1), fminf(kv2, kv3)));
            float delta = gmin;

            // ---- smallest j with kv==gmin: k-major, lowest lane
            unsigned long long m0 = __ballot(kv0 == gmin);
            unsigned long long m1 = __ballot(kv1 == gmin);
            unsigned long long m2 = __ballot(kv2 == gmin);
            unsigned long long m3 = __ballot(kv3 == gmin);
            int j1;
            if (m0)      j1 = 1   + (int)__builtin_ctzll(m0);
            else if (m1) j1 = 65  + (int)__builtin_ctzll(m1);
            else if (m2) j1 = 129 + (int)__builtin_ctzll(m2);
            else         j1 = 193 + (int)__builtin_ctzll(m3);

            // ---- matched row + its dual from j1's owner lane (j1 uniform)
            int kk = (j1 - 1) >> 6, ln = (j1 - 1) & 63;
            float us = (kk == 0) ? uslot[0] : (kk == 1) ? uslot[1]
                      : (kk == 2) ? uslot[2] : uslot[3];
            // fast path: packed shadow, no select chain ahead of the readlane
            int pi = (int)(((unsigned)rdlane_i((int)pp, ln) >> (kk * 8)) & 255u);

            // ---- issue next row's reads NOW (cm immutable: no hazard);
            //      ~120cyc latency overlaps updates + u0n readlane below
            int nr = (pi > 0 ? pi : 1) - 1;
            const float* nrow = cm + nr * QQ;
            float n0 = nrow[t];
            float n1 = nrow[64 + t];
            float n2 = nrow[128 + t];
            float n3 = nrow[192 + t];

            float u0n = rdlane_f(us, ln);

            // ---- updates (identical fp-op sequence to reference)
#pragma unroll
            for (int k = 0; k < 4; ++k) {
                if (usedm & (1 << k)) {
                    v[k] -= delta;
                    uslot[k] += delta;               // == u[p[j]] += delta
                } else if (k < nval) {
                    minv[k] -= delta;
                }
            }
            usent += delta;                          // == u[i] += delta (sentinel)

            if (pi == 0) { j0 = j1; break; }
            j0 = j1; u0 = u0n;
            c0 = n0; c1 = n1; c2 = n2; c3 = n3;
        }

        // ---- augment: flip matching along alternating path (uniform walk;
        //      way/p/u served from registers via readlane; entries frozen)
        {
            int jj = j0;
            while (jj != 0) {
                int jm = jj - 1, km = jm >> 6, lm = jm & 63;
                int ws = (km == 0) ? waysl[0] : (km == 1) ? waysl[1]
                        : (km == 2) ? waysl[2] : waysl[3];
                int jn = rdlane_i(ws, lm);
                int pnew; float unew;
                if (jn == 0) {
                    pnew = i;                        // p[0] = i (sentinel)
                    unew = usent;                    // u[i] accumulated this phase
                } else {
                    int jm2 = jn - 1, kn = jm2 >> 6, ln2 = jm2 & 63;
                    int   ps2 = (kn == 0) ? pslot[0] : (kn == 1) ? pslot[1]
                               : (kn == 2) ? pslot[2] : pslot[3];
                    float us2 = (kn == 0) ? uslot[0] : (kn == 1) ? uslot[1]
                               : (kn == 2) ? uslot[2] : uslot[3];
                    pnew = rdlane_i(ps2, ln2);
                    unew = rdlane_f(us2, ln2);
                }
                if (lm == t) {
                    pslot[km] = pnew;
                    uslot[km] = unew;
                    int sh = km * 8;
                    pp = (pp & ~(255u << sh)) | ((unsigned)pnew << sh);
                }
                jj = jn;
            }
        }
    }

    // pslot[k] = row matched to owned column jc; emit per-row matched cost
#pragma unroll
    for (int k = 0; k < 4; ++k) {
        if (k < nval) {
            int jc = 1 + t + 64 * k;
            int row = pslot[k] - 1;
            out[b * QQ + row] = cm[row * QQ + (jc - 1)];
        }
    }
}

// ---------------------------------------------------------------------------
extern "C" void kernel_launch(void* const* d_in, const int* in_sizes, int n_in,
                              void* d_out, int out_size, void* d_ws, size_t ws_size,
                              hipStream_t stream) {
    const float* pred_cat  = (const float*)d_in[0];
    const float* pred_bbox = (const float*)d_in[1];
    const int*   tar_cat   = (const int*)d_in[2];
    const float* tar_bbox  = (const float*)d_in[3];
    float* out = (float*)d_out;

    float* cost = (float*)d_ws;                     // B*Q*Q floats = 20.48 MB
    float* lse  = cost + (size_t)BB * QQ * QQ;      // B*Q floats

    lse_kernel<<<(BB * QQ + 255) / 256, 256, 0, stream>>>(pred_cat, lse);
    cost_kernel<<<((long)BB * QQ * QQ + 255) / 256, 256, 0, stream>>>(
        pred_cat, pred_bbox, tar_cat, tar_bbox, lse, cost);
    hungarian_kernel<<<BB, 64, 0, stream>>>(cost, out);
}